// Round 4
// baseline (348.759 us; speedup 1.0000x reference)
//
#include <hip/hip_runtime.h>
#include <math.h>

#pragma clang fp contract(off)

// Problem constants
#define B_   128
#define CI_  16
#define CO_  32
#define H_   32
#define W_   32
#define HO_  30
#define WO_  30
#define P_   900                 // HO*WO
#define CP_  (CO_*P_)            // 28800
#define N_   ((size_t)B_*CP_)    // 3686400 elements per tensor
#define NBLK_CONV (4*30*8)       // conv grid blocks = 960 (stats grouping preserved)
#define WSTRIDE_O 129600         // CI_*P_*9
#define WSTRIDE_C 8100           // P_*9
#define FFC_ (H_*W_)             // 1024  (channel stride in ff)
#define FFB_ (CI_*H_*W_)         // 16384 (batch stride in ff)
#define FFTOT_ (B_*FFB_)         // 2097152 total ff floats

// Per-buffer LDS layout (floats):
//   [0,2176)    weight groups: 32 groups x 68 (64 data + 4 pad)
//               element (o,w,k) at o*68 + w*8 + k   (o=0..31, w=0..7, k=0..7)
//               272B group stride => og-lanes hit banks 0/8/16/24 (was 4-way conflict)
//   [2176,2432) weight k=8 plane: (o,w) at 2176 + o*8 + w
//   [2432,3008) ff tile: (bb,r,cc) at 2432 + bb*36 + r*12 + cc
#define BUFSZ_ 3008

// d_out layout (4*N_ floats): [0,N)=soma, [N,2N)=spike, [2N,3N)=a_new, [3N,4N)=b_new.
// Slot [3N,4N) temporarily holds the f32 conv value; LIF reads it before
// overwriting with b_new.

// async global->LDS. LDS dest is wave-uniform base + lane*width.
typedef __attribute__((address_space(1))) const unsigned int gas_uint;
typedef __attribute__((address_space(3))) unsigned int las_uint;
__device__ __forceinline__ void gload_lds4(const float* g, float* l) {
    __builtin_amdgcn_global_load_lds((gas_uint*)g, (las_uint*)l, 4, 0, 0);
}
__device__ __forceinline__ void gload_lds16(const float* g, float* l) {
    __builtin_amdgcn_global_load_lds((gas_uint*)g, (las_uint*)l, 16, 0, 0);
}

// ---------------------------------------------------------------------------
// Kernel 1: locally-connected conv. Triple-buffered LDS staging with counted
// vmcnt barriers (stage-ahead-2 stays in flight across s_barrier), padded
// weight groups (68-float stride) to kill the 4-way ds_read_b128 bank
// conflict. Register blocking: thread = (2 o x 2 w x 4 b) -> 16 outputs.
// Per-output accumulation order (c outer, kh, kw; mul then add, no FMA) is
// bitwise identical to the reference. Grid/stat grouping unchanged (960).
// vmcnt(9): each stage issues 9-10 VMEM ops/wave; FIFO semantics => waiting
// to <=9 outstanding guarantees the 2-phases-old stage has fully landed.
// ---------------------------------------------------------------------------
__global__ __launch_bounds__(256, 4) void conv_kernel(
    const float* __restrict__ ff, const float* __restrict__ weight,
    const float* __restrict__ conv_bias, float* __restrict__ outf,
    double* __restrict__ part_sum, double* __restrict__ part_sumsq)
{
#pragma clang fp contract(off)
    const int tid = threadIdx.x;
    const int og  = (tid & 3) | ((tid >> 6) << 2);   // 0..15
    const int wg2 = (tid >> 2) & 3;                  // 0..3
    const int bg  = (tid >> 4) & 3;                  // 0..3
    const int wave = tid >> 6;
    const int wt = blockIdx.x;          // 0..3
    const int h  = blockIdx.y;          // 0..29
    const int b0 = blockIdx.z * 16;     // 16 batches per block
    const int w0 = wt * 8 + wg2 * 2;
    const bool val = !(wt == 3 && wg2 == 3);

    __shared__ float lds[3 * BUFSZ_];

    // ---- c-independent staging offsets (all in-bounds by construction) ----
    // weight element s = q*256 + tid -> (o = s>>6, w = (s>>3)&7, k = s&7)
    int wq_off[8];
#pragma unroll
    for (int q = 0; q < 8; ++q) {
        int s = q * 256 + tid;
        int o = s >> 6, w = (s >> 3) & 7, k = s & 7;
        int colc = wt * 8 + w; if (colc > 29) colc = 29;   // edge clamp (garbage -> invalid threads only)
        wq_off[q] = o * WSTRIDE_O + (h * WO_ + colc) * 9 + k;
    }
    int w8_off;
    {
        int o = tid >> 3, w = tid & 7;
        int colc = wt * 8 + w; if (colc > 29) colc = 29;
        w8_off = o * WSTRIDE_O + (h * WO_ + colc) * 9 + 8;
    }
    const bool fon = (tid < 144);
    int f_off = 0;
    if (fon) {
        int s0 = 4 * tid;               // 0,4,...,572
        int bb = s0 / 36, rm = s0 % 36, r = rm / 12, cc0 = rm % 12;
        f_off = (b0 + bb) * FFB_ + (h + r) * W_ + wt * 8 + cc0;   // 16B-aligned
    }

    float acc[2][2][4];
#pragma unroll
    for (int oo = 0; oo < 2; ++oo)
#pragma unroll
        for (int ww = 0; ww < 2; ++ww)
#pragma unroll
            for (int j = 0; j < 4; ++j) acc[oo][ww][j] = 0.f;

    auto stage = [&](int c, float* buf) {
        const float* wsrc = weight + c * WSTRIDE_C;
#pragma unroll
        for (int q = 0; q < 8; ++q)
            gload_lds4(wsrc + wq_off[q], buf + (q * 4 + wave) * 68);
        gload_lds4(wsrc + w8_off, buf + 2176 + (wave << 6));
        if (fon) {
            int g = f_off + c * FFC_;
            if (g > FFTOT_ - 4) g = FFTOT_ - 4;   // single corner clamp (garbage slots only)
            gload_lds16(ff + g, buf + 2432 + (wave << 8));
        }
    };

    const int o0 = og * 2;
    auto compute_c = [&](const float* buf) {
        float wk[2][2][9];
#pragma unroll
        for (int oo = 0; oo < 2; ++oo)
#pragma unroll
            for (int ww = 0; ww < 2; ++ww) {
                const int o = o0 + oo, w = wg2 * 2 + ww;
                const float* wp = buf + o * 68 + w * 8;           // 16B-aligned
                const float4 a = *reinterpret_cast<const float4*>(wp);
                const float4 b = *reinterpret_cast<const float4*>(wp + 4);
                wk[oo][ww][0] = a.x; wk[oo][ww][1] = a.y; wk[oo][ww][2] = a.z; wk[oo][ww][3] = a.w;
                wk[oo][ww][4] = b.x; wk[oo][ww][5] = b.y; wk[oo][ww][6] = b.z; wk[oo][ww][7] = b.w;
                wk[oo][ww][8] = buf[2176 + o * 8 + w];
            }
        const float* fbase = buf + 2432;
#pragma unroll
        for (int j = 0; j < 4; ++j) {
            const int bb = bg * 4 + j;
            float fr[3][4];
#pragma unroll
            for (int r = 0; r < 3; ++r) {
                const float2 u = *reinterpret_cast<const float2*>(fbase + bb * 36 + r * 12 + wg2 * 2);
                const float2 v = *reinterpret_cast<const float2*>(fbase + bb * 36 + r * 12 + wg2 * 2 + 2);
                fr[r][0] = u.x; fr[r][1] = u.y; fr[r][2] = v.x; fr[r][3] = v.y;
            }
#pragma unroll
            for (int oo = 0; oo < 2; ++oo)
#pragma unroll
                for (int ww = 0; ww < 2; ++ww) {
                    float a = acc[oo][ww][j];
#pragma unroll
                    for (int kh = 0; kh < 3; ++kh)
#pragma unroll
                        for (int kw = 0; kw < 3; ++kw) {
                            float prod = wk[oo][ww][kh * 3 + kw] * fr[kh][ww + kw];
                            a = a + prod;      // no FMA, (c,kh,kw) order
                        }
                    acc[oo][ww][j] = a;
                }
        }
    };

    // triple-buffer pipeline, stage-ahead-2, counted vmcnt at each barrier
    float* pa = lds;                 // phase t   (being computed)
    float* pb = lds + BUFSZ_;        // phase t+1 (in flight / landed)
    float* pc = lds + 2 * BUFSZ_;    // phase t+2 (staged this phase)
    stage(0, pa);
    stage(1, pb);
#pragma unroll 3
    for (int t = 0; t < CI_ - 1; ++t) {
        // my stage(t) done (<=9 left are the newer stages' tail); sync all waves
        asm volatile("s_waitcnt vmcnt(9)\n\ts_barrier" ::: "memory");
        if (t + 2 < CI_) stage(t + 2, pc);   // pc's readers all passed the barrier
        compute_c(pa);
        float* tmp = pa; pa = pb; pb = pc; pc = tmp;
    }
    asm volatile("s_waitcnt vmcnt(0)\n\ts_barrier" ::: "memory");
    compute_c(pa);                    // channel 15

    // epilogue: bias, park conv values, exact f64 per-block per-channel stats
    double s1[2] = {0.0, 0.0}, s2[2] = {0.0, 0.0};
    if (val) {
#pragma unroll
        for (int oo = 0; oo < 2; ++oo) {
            const int o = o0 + oo;
            const int pidx = o * P_ + h * WO_ + w0;
            const float2 bi = *reinterpret_cast<const float2*>(conv_bias + pidx);
#pragma unroll
            for (int j = 0; j < 4; ++j) {
                const int b = b0 + bg * 4 + j;
                const size_t n = (size_t)b * CP_ + (size_t)pidx;
                float v0 = acc[oo][0][j] + bi.x;     // f32, same as ref
                float v1 = acc[oo][1][j] + bi.y;
                *reinterpret_cast<float2*>(outf + 3 * N_ + n) = make_float2(v0, v1);
                double d0 = (double)v0, d1 = (double)v1;
                s1[oo] += d0; s2[oo] += d0 * d0;
                s1[oo] += d1; s2[oo] += d1 * d1;
            }
        }
    }
    // deterministic reduce over the 16 lanes (stride 4) sharing og
#pragma unroll
    for (int d = 4; d < 64; d <<= 1) {
#pragma unroll
        for (int oo = 0; oo < 2; ++oo) {
            s1[oo] += __shfl_xor(s1[oo], d);
            s2[oo] += __shfl_xor(s2[oo], d);
        }
    }
    if ((tid & 60) == 0) {               // wg2==0 && bg==0
        int blk = (blockIdx.z * 30 + blockIdx.y) * 4 + blockIdx.x;   // 0..959
#pragma unroll
        for (int oo = 0; oo < 2; ++oo) {
            part_sum  [blk * CO_ + o0 + oo] = s1[oo];
            part_sumsq[blk * CO_ + o0 + oo] = s2[oo];
        }
    }
}

// ---------------------------------------------------------------------------
// Kernel 2: BN finalize — deterministic f64 reduction of partials, then
// f32 mean / inv_std per channel. UNCHANGED.
// ---------------------------------------------------------------------------
__global__ __launch_bounds__(256) void bn_finalize(
    const double* __restrict__ part_sum, const double* __restrict__ part_sumsq,
    float* __restrict__ Mb)
{
#pragma clang fp contract(off)
    const int o = blockIdx.x;
    const int tid = threadIdx.x;
    double s1 = 0.0, s2 = 0.0;
    for (int i = tid; i < NBLK_CONV; i += 256) {
        s1 += part_sum[i * CO_ + o];
        s2 += part_sumsq[i * CO_ + o];
    }
    __shared__ double r1[256], r2[256];
    r1[tid] = s1; r2[tid] = s2;
    __syncthreads();
    for (int s = 128; s > 0; s >>= 1) {
        if (tid < s) { r1[tid] += r1[tid + s]; r2[tid] += r2[tid + s]; }
        __syncthreads();
    }
    if (tid == 0) {
        const double cnt = (double)(B_ * (size_t)P_);
        double mean = r1[0] / cnt;
        float meanf = (float)mean;
        double md = (double)meanf;
        double var = r2[0] / cnt - 2.0 * md * (r1[0] / cnt) + md * md;
        float varf = (float)var;
        float invf = 1.0f / sqrtf(varf + 1e-5f);
        Mb[o]       = meanf;
        Mb[CO_ + o] = invf;
    }
}

// ---------------------------------------------------------------------------
// Kernel 3: fused recurrent-bmm + LIF. UNCHANGED from R3 (near BW floor):
// register prefetch + raw `s_waitcnt lgkmcnt(0); s_barrier` (loads stay in
// flight across barriers); 1024 thr = 32 i x 32 p; grid (29, 16).
// ---------------------------------------------------------------------------
__global__ __launch_bounds__(1024) void lif_rec_kernel(
    float* __restrict__ outf, const float* __restrict__ local_rec,
    const float* __restrict__ tau_m, const float* __restrict__ tau_adp,
    const float* __restrict__ tau_a, const float* __restrict__ Mb,
    const float* __restrict__ gamma, const float* __restrict__ beta,
    const float* __restrict__ fb, const float* __restrict__ soma_t,
    const float* __restrict__ spk_t, const float* __restrict__ a_curr,
    const float* __restrict__ b_t)
{
#pragma clang fp contract(off)
    const int tid = threadIdx.x;
    const int pp  = tid & 31;
    const int i   = tid >> 5;            // channel 0..31
    const int p   = blockIdx.x * 32 + pp;
    const bool pv = (p < P_);
    const int b0  = blockIdx.y * 8;

    float L[32];
    float meanf = 0.f, invf = 0.f, gm = 0.f, be = 0.f;
    float al = 0.f, rh = 0.f, et = 0.f;
    int rem = 0;
    if (pv) {
        const float4* lp = reinterpret_cast<const float4*>(local_rec + (size_t)p * (CO_ * CO_) + i * CO_);
#pragma unroll
        for (int q = 0; q < 8; ++q) {
            float4 v = lp[q];
            L[4 * q] = v.x; L[4 * q + 1] = v.y; L[4 * q + 2] = v.z; L[4 * q + 3] = v.w;
        }
        rem = i * P_ + p;
        meanf = Mb[i]; invf = Mb[CO_ + i];
        gm = gamma[i]; be = beta[i];
        // identical f32 ops to the original tau table: f32 divide then f32 exp
        al = expf(-0.5f / tau_m[rem]);
        rh = expf(-0.5f / tau_adp[rem]);
        et = expf(-0.5f / tau_a[rem]);
    }

    __shared__ float sp[2][CO_][32];

    // prologue: iteration-0 operands into registers
    size_t n = (size_t)b0 * CP_ + (size_t)rem;
    float sk_c = 0.f, cv_c = 0.f, bt_c = 0.f, ac_c = 0.f, fb_c = 0.f, so_c = 0.f;
    if (pv) {
        sk_c = spk_t[n]; cv_c = outf[3 * N_ + n]; bt_c = b_t[n];
        ac_c = a_curr[n]; fb_c = fb[n]; so_c = soma_t[n];
    }

#pragma unroll
    for (int bb = 0; bb < 8; ++bb) {
        const int cb = bb & 1;
        if (pv) sp[cb][i][pp] = sk_c;
        // prefetch next iteration BEFORE the barrier (stays in flight: the
        // raw barrier below drains lgkmcnt only, not vmcnt)
        float sk_n = 0.f, cv_n = 0.f, bt_n = 0.f, ac_n = 0.f, fb_n = 0.f, so_n = 0.f;
        if (bb + 1 < 8 && pv) {
            const size_t nn = n + (size_t)CP_;
            sk_n = spk_t[nn]; cv_n = outf[3 * N_ + nn]; bt_n = b_t[nn];
            ac_n = a_curr[nn]; fb_n = fb[nn]; so_n = soma_t[nn];
        }
        asm volatile("s_waitcnt lgkmcnt(0)\n\ts_barrier" ::: "memory");
        if (pv) {
            // rec: sequential f32 dot over j, no FMA (np einsum order)
            float rec = 0.f;
#pragma unroll
            for (int j = 0; j < CO_; ++j) {
                float prod = L[j] * sp[cb][j][pp];
                rec = rec + prod;
            }

            // BN exactly as reference
            float t  = cv_c - meanf;
            float x  = t * invf;
            float xg = x * gm;
            float cx = xg + be;
            cx = cx + rec;

            // b_new = rho*b_t + (1-rho)*spk
            float rb  = rh * bt_c;
            float omr = 1.0f - rh;
            float os  = omr * sk_c;
            float bn  = rb + os;
            // new_thre = 0.1 + 1.8*b_new
            float tb = 1.8f * bn;
            float th = 0.1f + tb;
            // a_new = eta*a_curr + fb
            float ea = et * ac_c;
            float an = ea + fb_c;
            // sigmoid
            float sg = 1.0f / (1.0f + expf(-an));
            // soma_new = alpha*soma + (sig-0.5) + cx - thre*spk  (left-to-right)
            float as = al * so_c;
            float s5 = sg - 0.5f;
            float u1 = as + s5;
            float u2 = u1 + cx;
            float ts = th * sk_c;
            float sn = u2 - ts;

            outf[n]          = sn;
            outf[N_ + n]     = ((sn - th) > 0.0f) ? 1.f : 0.f;
            outf[2 * N_ + n] = an;
            outf[3 * N_ + n] = bn;                                // overwrites conv
        }
        sk_c = sk_n; cv_c = cv_n; bt_c = bt_n; ac_c = ac_n; fb_c = fb_n; so_c = so_n;
        n += (size_t)CP_;
    }
}

extern "C" void kernel_launch(void* const* d_in, const int* in_sizes, int n_in,
                              void* d_out, int out_size, void* d_ws, size_t ws_size,
                              hipStream_t stream)
{
    const float* ff        = (const float*)d_in[0];
    const float* fb        = (const float*)d_in[1];
    const float* soma_t    = (const float*)d_in[2];
    const float* spk_t     = (const float*)d_in[3];
    const float* a_curr    = (const float*)d_in[4];
    const float* b_t       = (const float*)d_in[5];
    const float* weight    = (const float*)d_in[6];
    const float* conv_bias = (const float*)d_in[7];
    const float* local_rec = (const float*)d_in[8];
    const float* gamma     = (const float*)d_in[9];
    const float* beta      = (const float*)d_in[10];
    const float* tau_m     = (const float*)d_in[11];
    const float* tau_adp   = (const float*)d_in[12];
    const float* tau_a     = (const float*)d_in[13];

    // ws: f64 partials then Mb (~0.5 MB total)
    double* part_sum = (double*)d_ws;                       // NBLK_CONV*CO_
    double* part_sq  = part_sum + (size_t)NBLK_CONV * CO_;  // NBLK_CONV*CO_
    float*  Mb       = (float*)(part_sq + (size_t)NBLK_CONV * CO_);  // 64

    float* outf = (float*)d_out;

    conv_kernel<<<dim3(4, 30, 8), 256, 0, stream>>>(
        ff, weight, conv_bias, outf, part_sum, part_sq);
    bn_finalize<<<dim3(CO_), 256, 0, stream>>>(part_sum, part_sq, Mb);
    lif_rec_kernel<<<dim3(29, 16), 1024, 0, stream>>>(
        outf, local_rec, tau_m, tau_adp, tau_a, Mb, gamma, beta,
        fb, soma_t, spk_t, a_curr, b_t);
}

// Round 5
// 115.011 us; speedup vs baseline: 3.0324x; 3.0324x over previous
//
#include <hip/hip_runtime.h>
#include <math.h>

#pragma clang fp contract(off)

// Problem constants
#define B_   128
#define CI_  16
#define CO_  32
#define H_   32
#define W_   32
#define HO_  30
#define WO_  30
#define P_   900                 // HO*WO
#define CP_  (CO_*P_)            // 28800
#define N_   ((size_t)B_*CP_)    // 3686400 elements per tensor
#define NBLK_CONV (4*30*8)       // conv grid blocks = 960 (stats grouping preserved)
#define WSTRIDE_O 129600         // CI_*P_*9
#define WSTRIDE_C 8100           // P_*9
#define FFC_ (H_*W_)             // 1024  (channel stride in ff)
#define FFB_ (CI_*H_*W_)         // 16384 (batch stride in ff)
#define FFTOT_ (B_*FFB_)         // 2097152 total ff floats

// d_out layout (4*N_ floats): [0,N)=soma, [N,2N)=spike, [2N,3N)=a_new, [3N,4N)=b_new.
// Slot [3N,4N) temporarily holds the f32 conv value; LIF reads it before
// overwriting with b_new.

// async global->LDS. LDS dest is wave-uniform base + lane*width.
typedef __attribute__((address_space(1))) const unsigned int gas_uint;
typedef __attribute__((address_space(3))) unsigned int las_uint;
__device__ __forceinline__ void gload_lds4(const float* g, float* l) {
    __builtin_amdgcn_global_load_lds((gas_uint*)g, (las_uint*)l, 4, 0, 0);
}
__device__ __forceinline__ void gload_lds16(const float* g, float* l) {
    __builtin_amdgcn_global_load_lds((gas_uint*)g, (las_uint*)l, 16, 0, 0);
}

// ---------------------------------------------------------------------------
// Kernel 1: locally-connected conv. EXACTLY the R3 structure (LDS-staged via
// lane-linear global_load_lds, static double-buffer literals, __syncthreads,
// register blocking thread = 2o x 2w x 4b) with ONE change: weight groups
// padded to 68 floats (272B stride) so the og-lanes' ds_read_b128 addresses
// land on banks 0/8/16/24 instead of all on bank 0 (was a 4-way conflict,
// 1.3e7 conflict cycles). wg2 pairs are 2-way (free), bg lanes broadcast.
// Weight LDS: group g=(o) at g*68, element (o,w,k) at o*68 + w*8 + k;
//   k=8 plane at 2176 + o*8 + w. Staged as 8 wave-chunks (g = q*4+wave).
// Per-output accumulation order (c outer, kh, kw; mul then add, no FMA) is
// bitwise identical to the reference. Grid/stat grouping unchanged (960).
// ---------------------------------------------------------------------------
__global__ __launch_bounds__(256) void conv_kernel(
    const float* __restrict__ ff, const float* __restrict__ weight,
    const float* __restrict__ conv_bias, float* __restrict__ outf,
    double* __restrict__ part_sum, double* __restrict__ part_sumsq)
{
#pragma clang fp contract(off)
    const int tid = threadIdx.x;
    const int og  = (tid & 3) | ((tid >> 6) << 2);   // 0..15
    const int wg2 = (tid >> 2) & 3;                  // 0..3
    const int bg  = (tid >> 4) & 3;                  // 0..3
    const int wave = tid >> 6;
    const int wt = blockIdx.x;          // 0..3
    const int h  = blockIdx.y;          // 0..29
    const int b0 = blockIdx.z * 16;     // 16 batches per block
    const int w0 = wt * 8 + wg2 * 2;
    const bool val = !(wt == 3 && wg2 == 3);
    const int wwave = tid & ~63;        // wave-uniform lane-0 tid

    __shared__ float wgl[2][2432];      // [buf][o*68 + w*8 + k] + k8 plane at 2176
    __shared__ float ffs[2][576];       // [buf][bb*36 + r*12 + cc]

    // ---- c-independent staging offsets (all in-bounds by construction) ----
    // weight element s = q*256 + tid -> (o = s>>6, w = (s>>3)&7, k = s&7)
    int wq_off[8];
#pragma unroll
    for (int q = 0; q < 8; ++q) {
        int s = q * 256 + tid;
        int o = s >> 6, w = (s >> 3) & 7, k = s & 7;
        int colc = wt * 8 + w; if (colc > 29) colc = 29;   // edge clamp (garbage -> invalid threads only)
        wq_off[q] = o * WSTRIDE_O + (h * WO_ + colc) * 9 + k;
    }
    int w8_off;
    {
        int o = tid >> 3, w = tid & 7;
        int colc = wt * 8 + w; if (colc > 29) colc = 29;
        w8_off = o * WSTRIDE_O + (h * WO_ + colc) * 9 + 8;
    }
    const bool fon = (tid < 144);
    int f_off = 0;
    if (fon) {
        int s0 = 4 * tid;               // 0,4,...,572
        int bb = s0 / 36, rm = s0 % 36, r = rm / 12, cc0 = rm % 12;
        f_off = (b0 + bb) * FFB_ + (h + r) * W_ + wt * 8 + cc0;   // 16B-aligned
    }

    float acc[2][2][4];
#pragma unroll
    for (int oo = 0; oo < 2; ++oo)
#pragma unroll
        for (int ww = 0; ww < 2; ++ww)
#pragma unroll
            for (int j = 0; j < 4; ++j) acc[oo][ww][j] = 0.f;

    auto stage = [&](int c, int buf) {
        const float* wsrc = weight + c * WSTRIDE_C;
#pragma unroll
        for (int q = 0; q < 8; ++q)
            gload_lds4(wsrc + wq_off[q], &wgl[buf][(q * 4 + wave) * 68]);
        gload_lds4(wsrc + w8_off, &wgl[buf][2176 + (wave << 6)]);
        if (fon) {
            int g = f_off + c * FFC_;
            if (g > FFTOT_ - 4) g = FFTOT_ - 4;   // corner clamp (garbage slots only)
            gload_lds16(ff + g, &ffs[buf][4 * wwave]);
        }
    };

    const int o0 = og * 2;
    auto compute_c = [&](int buf) {
        float wk[2][2][9];
#pragma unroll
        for (int oo = 0; oo < 2; ++oo)
#pragma unroll
            for (int ww = 0; ww < 2; ++ww) {
                const int o = o0 + oo, w = wg2 * 2 + ww;
                const float* wp = &wgl[buf][o * 68 + w * 8];      // 272B group stride, 16B-aligned
                const float4 a = *reinterpret_cast<const float4*>(wp);
                const float4 b = *reinterpret_cast<const float4*>(wp + 4);
                wk[oo][ww][0] = a.x; wk[oo][ww][1] = a.y; wk[oo][ww][2] = a.z; wk[oo][ww][3] = a.w;
                wk[oo][ww][4] = b.x; wk[oo][ww][5] = b.y; wk[oo][ww][6] = b.z; wk[oo][ww][7] = b.w;
                wk[oo][ww][8] = wgl[buf][2176 + o * 8 + w];
            }
#pragma unroll
        for (int j = 0; j < 4; ++j) {
            const int bb = bg * 4 + j;
            float fr[3][4];
#pragma unroll
            for (int r = 0; r < 3; ++r) {
                const float2 u = *reinterpret_cast<const float2*>(&ffs[buf][bb * 36 + r * 12 + wg2 * 2]);
                const float2 v = *reinterpret_cast<const float2*>(&ffs[buf][bb * 36 + r * 12 + wg2 * 2 + 2]);
                fr[r][0] = u.x; fr[r][1] = u.y; fr[r][2] = v.x; fr[r][3] = v.y;
            }
#pragma unroll
            for (int oo = 0; oo < 2; ++oo)
#pragma unroll
                for (int ww = 0; ww < 2; ++ww) {
                    float a = acc[oo][ww][j];
#pragma unroll
                    for (int kh = 0; kh < 3; ++kh)
#pragma unroll
                        for (int kw = 0; kw < 3; ++kw) {
                            float prod = wk[oo][ww][kh * 3 + kw] * fr[kh][ww + kw];
                            a = a + prod;      // no FMA, (c,kh,kw) order
                        }
                    acc[oo][ww][j] = a;
                }
        }
    };

    stage(0, 0);
    __syncthreads();
    for (int cs = 0; cs < CI_; cs += 2) {
        if (cs + 1 < CI_) stage(cs + 1, 1);   // prefetch overlaps compute
        compute_c(0);
        __syncthreads();
        if (cs + 2 < CI_) stage(cs + 2, 0);
        compute_c(1);
        __syncthreads();
    }

    // epilogue: bias, park conv values, exact f64 per-block per-channel stats
    double s1[2] = {0.0, 0.0}, s2[2] = {0.0, 0.0};
    if (val) {
#pragma unroll
        for (int oo = 0; oo < 2; ++oo) {
            const int o = o0 + oo;
            const int pidx = o * P_ + h * WO_ + w0;
            const float2 bi = *reinterpret_cast<const float2*>(conv_bias + pidx);
#pragma unroll
            for (int j = 0; j < 4; ++j) {
                const int b = b0 + bg * 4 + j;
                const size_t n = (size_t)b * CP_ + (size_t)pidx;
                float v0 = acc[oo][0][j] + bi.x;     // f32, same as ref
                float v1 = acc[oo][1][j] + bi.y;
                *reinterpret_cast<float2*>(outf + 3 * N_ + n) = make_float2(v0, v1);
                double d0 = (double)v0, d1 = (double)v1;
                s1[oo] += d0; s2[oo] += d0 * d0;
                s1[oo] += d1; s2[oo] += d1 * d1;
            }
        }
    }
    // deterministic reduce over the 16 lanes (stride 4) sharing og
#pragma unroll
    for (int d = 4; d < 64; d <<= 1) {
#pragma unroll
        for (int oo = 0; oo < 2; ++oo) {
            s1[oo] += __shfl_xor(s1[oo], d);
            s2[oo] += __shfl_xor(s2[oo], d);
        }
    }
    if ((tid & 60) == 0) {               // wg2==0 && bg==0
        int blk = (blockIdx.z * 30 + blockIdx.y) * 4 + blockIdx.x;   // 0..959
#pragma unroll
        for (int oo = 0; oo < 2; ++oo) {
            part_sum  [blk * CO_ + o0 + oo] = s1[oo];
            part_sumsq[blk * CO_ + o0 + oo] = s2[oo];
        }
    }
}

// ---------------------------------------------------------------------------
// Kernel 2: BN finalize — deterministic f64 reduction of partials, then
// f32 mean / inv_std per channel. UNCHANGED.
// ---------------------------------------------------------------------------
__global__ __launch_bounds__(256) void bn_finalize(
    const double* __restrict__ part_sum, const double* __restrict__ part_sumsq,
    float* __restrict__ Mb)
{
#pragma clang fp contract(off)
    const int o = blockIdx.x;
    const int tid = threadIdx.x;
    double s1 = 0.0, s2 = 0.0;
    for (int i = tid; i < NBLK_CONV; i += 256) {
        s1 += part_sum[i * CO_ + o];
        s2 += part_sumsq[i * CO_ + o];
    }
    __shared__ double r1[256], r2[256];
    r1[tid] = s1; r2[tid] = s2;
    __syncthreads();
    for (int s = 128; s > 0; s >>= 1) {
        if (tid < s) { r1[tid] += r1[tid + s]; r2[tid] += r2[tid + s]; }
        __syncthreads();
    }
    if (tid == 0) {
        const double cnt = (double)(B_ * (size_t)P_);
        double mean = r1[0] / cnt;
        float meanf = (float)mean;
        double md = (double)meanf;
        double var = r2[0] / cnt - 2.0 * md * (r1[0] / cnt) + md * md;
        float varf = (float)var;
        float invf = 1.0f / sqrtf(varf + 1e-5f);
        Mb[o]       = meanf;
        Mb[CO_ + o] = invf;
    }
}

// ---------------------------------------------------------------------------
// Kernel 3: fused recurrent-bmm + LIF. UNCHANGED from R3 (near BW floor):
// register prefetch + raw `s_waitcnt lgkmcnt(0); s_barrier` (loads stay in
// flight across barriers); 1024 thr = 32 i x 32 p; grid (29, 16).
// ---------------------------------------------------------------------------
__global__ __launch_bounds__(1024) void lif_rec_kernel(
    float* __restrict__ outf, const float* __restrict__ local_rec,
    const float* __restrict__ tau_m, const float* __restrict__ tau_adp,
    const float* __restrict__ tau_a, const float* __restrict__ Mb,
    const float* __restrict__ gamma, const float* __restrict__ beta,
    const float* __restrict__ fb, const float* __restrict__ soma_t,
    const float* __restrict__ spk_t, const float* __restrict__ a_curr,
    const float* __restrict__ b_t)
{
#pragma clang fp contract(off)
    const int tid = threadIdx.x;
    const int pp  = tid & 31;
    const int i   = tid >> 5;            // channel 0..31
    const int p   = blockIdx.x * 32 + pp;
    const bool pv = (p < P_);
    const int b0  = blockIdx.y * 8;

    float L[32];
    float meanf = 0.f, invf = 0.f, gm = 0.f, be = 0.f;
    float al = 0.f, rh = 0.f, et = 0.f;
    int rem = 0;
    if (pv) {
        const float4* lp = reinterpret_cast<const float4*>(local_rec + (size_t)p * (CO_ * CO_) + i * CO_);
#pragma unroll
        for (int q = 0; q < 8; ++q) {
            float4 v = lp[q];
            L[4 * q] = v.x; L[4 * q + 1] = v.y; L[4 * q + 2] = v.z; L[4 * q + 3] = v.w;
        }
        rem = i * P_ + p;
        meanf = Mb[i]; invf = Mb[CO_ + i];
        gm = gamma[i]; be = beta[i];
        // identical f32 ops to the original tau table: f32 divide then f32 exp
        al = expf(-0.5f / tau_m[rem]);
        rh = expf(-0.5f / tau_adp[rem]);
        et = expf(-0.5f / tau_a[rem]);
    }

    __shared__ float sp[2][CO_][32];

    // prologue: iteration-0 operands into registers
    size_t n = (size_t)b0 * CP_ + (size_t)rem;
    float sk_c = 0.f, cv_c = 0.f, bt_c = 0.f, ac_c = 0.f, fb_c = 0.f, so_c = 0.f;
    if (pv) {
        sk_c = spk_t[n]; cv_c = outf[3 * N_ + n]; bt_c = b_t[n];
        ac_c = a_curr[n]; fb_c = fb[n]; so_c = soma_t[n];
    }

#pragma unroll
    for (int bb = 0; bb < 8; ++bb) {
        const int cb = bb & 1;
        if (pv) sp[cb][i][pp] = sk_c;
        // prefetch next iteration BEFORE the barrier (stays in flight: the
        // raw barrier below drains lgkmcnt only, not vmcnt)
        float sk_n = 0.f, cv_n = 0.f, bt_n = 0.f, ac_n = 0.f, fb_n = 0.f, so_n = 0.f;
        if (bb + 1 < 8 && pv) {
            const size_t nn = n + (size_t)CP_;
            sk_n = spk_t[nn]; cv_n = outf[3 * N_ + nn]; bt_n = b_t[nn];
            ac_n = a_curr[nn]; fb_n = fb[nn]; so_n = soma_t[nn];
        }
        asm volatile("s_waitcnt lgkmcnt(0)\n\ts_barrier" ::: "memory");
        if (pv) {
            // rec: sequential f32 dot over j, no FMA (np einsum order)
            float rec = 0.f;
#pragma unroll
            for (int j = 0; j < CO_; ++j) {
                float prod = L[j] * sp[cb][j][pp];
                rec = rec + prod;
            }

            // BN exactly as reference
            float t  = cv_c - meanf;
            float x  = t * invf;
            float xg = x * gm;
            float cx = xg + be;
            cx = cx + rec;

            // b_new = rho*b_t + (1-rho)*spk
            float rb  = rh * bt_c;
            float omr = 1.0f - rh;
            float os  = omr * sk_c;
            float bn  = rb + os;
            // new_thre = 0.1 + 1.8*b_new
            float tb = 1.8f * bn;
            float th = 0.1f + tb;
            // a_new = eta*a_curr + fb
            float ea = et * ac_c;
            float an = ea + fb_c;
            // sigmoid
            float sg = 1.0f / (1.0f + expf(-an));
            // soma_new = alpha*soma + (sig-0.5) + cx - thre*spk  (left-to-right)
            float as = al * so_c;
            float s5 = sg - 0.5f;
            float u1 = as + s5;
            float u2 = u1 + cx;
            float ts = th * sk_c;
            float sn = u2 - ts;

            outf[n]          = sn;
            outf[N_ + n]     = ((sn - th) > 0.0f) ? 1.f : 0.f;
            outf[2 * N_ + n] = an;
            outf[3 * N_ + n] = bn;                                // overwrites conv
        }
        sk_c = sk_n; cv_c = cv_n; bt_c = bt_n; ac_c = ac_n; fb_c = fb_n; so_c = so_n;
        n += (size_t)CP_;
    }
}

extern "C" void kernel_launch(void* const* d_in, const int* in_sizes, int n_in,
                              void* d_out, int out_size, void* d_ws, size_t ws_size,
                              hipStream_t stream)
{
    const float* ff        = (const float*)d_in[0];
    const float* fb        = (const float*)d_in[1];
    const float* soma_t    = (const float*)d_in[2];
    const float* spk_t     = (const float*)d_in[3];
    const float* a_curr    = (const float*)d_in[4];
    const float* b_t       = (const float*)d_in[5];
    const float* weight    = (const float*)d_in[6];
    const float* conv_bias = (const float*)d_in[7];
    const float* local_rec = (const float*)d_in[8];
    const float* gamma     = (const float*)d_in[9];
    const float* beta      = (const float*)d_in[10];
    const float* tau_m     = (const float*)d_in[11];
    const float* tau_adp   = (const float*)d_in[12];
    const float* tau_a     = (const float*)d_in[13];

    // ws: f64 partials then Mb (~0.5 MB total)
    double* part_sum = (double*)d_ws;                       // NBLK_CONV*CO_
    double* part_sq  = part_sum + (size_t)NBLK_CONV * CO_;  // NBLK_CONV*CO_
    float*  Mb       = (float*)(part_sq + (size_t)NBLK_CONV * CO_);  // 64

    float* outf = (float*)d_out;

    conv_kernel<<<dim3(4, 30, 8), 256, 0, stream>>>(
        ff, weight, conv_bias, outf, part_sum, part_sq);
    bn_finalize<<<dim3(CO_), 256, 0, stream>>>(part_sum, part_sq, Mb);
    lif_rec_kernel<<<dim3(29, 16), 1024, 0, stream>>>(
        outf, local_rec, tau_m, tau_adp, tau_a, Mb, gamma, beta,
        fb, soma_t, spk_t, a_curr, b_t);
}